// Round 1
// baseline (963.021 us; speedup 1.0000x reference)
//
#include <hip/hip_runtime.h>
#include <hip/hip_bf16.h>
#include <cstddef>

#define RES 256
#define NCH 32
#define NPT 131072   // points per batch
#define NB  4

// ---------------------------------------------------------------------------
// Transpose triplanes [bp][c][y][x] -> [bp][y][x][c]  (bp = b*3+plane, 12 total)
// so one texel's 32 channels are 128 contiguous bytes.
// ---------------------------------------------------------------------------
__global__ __launch_bounds__(256) void transpose_kernel(
    const float* __restrict__ in, float* __restrict__ out)
{
    __shared__ float tile[NCH][64 + 1];   // +1 pad: breaks bank aliasing
    const int bp = blockIdx.z;
    const int y  = blockIdx.y;
    const int x0 = blockIdx.x * 64;
    const int t  = threadIdx.x;

    // load: [c][x] coalesced along x
    {
        const float* src = in + (size_t)bp * NCH * RES * RES + (size_t)y * RES + x0;
        const int xi = t & 63;
        const int ci = t >> 6;           // 0..3
        #pragma unroll
        for (int j = 0; j < 8; ++j) {
            const int c = ci + j * 4;
            tile[c][xi] = src[(size_t)c * RES * RES + xi];
        }
    }
    __syncthreads();
    // store: [x][c] coalesced along c (and consecutive x)
    {
        float* dst = out + ((size_t)bp * RES * RES + (size_t)y * RES + x0) * NCH;
        const int co = t & 31;
        const int xo = t >> 5;           // 0..7
        #pragma unroll
        for (int j = 0; j < 8; ++j) {
            const int x = xo + j * 8;
            dst[(size_t)x * NCH + co] = tile[co][x];
        }
    }
}

// ---------------------------------------------------------------------------
// Fused: bilinear-sample 3 planes, multiply features, run 32->128->128->1 MLP.
// One thread per point. TRANSPOSED selects [y][x][c] (fast) vs [c][y][x] layout.
// ---------------------------------------------------------------------------
template<bool TRANSPOSED>
__global__ __launch_bounds__(256) void fused_kernel(
    const float* __restrict__ planes,
    const float* __restrict__ coords,
    const float* __restrict__ w0, const float* __restrict__ b0,
    const float* __restrict__ w1, const float* __restrict__ b1,
    const float* __restrict__ w2, const float* __restrict__ b2,
    float* __restrict__ out)
{
    const int t = blockIdx.x * 256 + threadIdx.x;     // global point id, < NB*NPT
    const int b = t >> 17;                            // NPT = 2^17

    const float cx = coords[(size_t)t * 3 + 0];
    const float cy = coords[(size_t)t * 3 + 1];
    const float cz = coords[(size_t)t * 3 + 2];

    float feat[NCH];

    #pragma unroll
    for (int p = 0; p < 3; ++p) {
        // plane 0: (x,y)  plane 1: (y,z)  plane 2: (x,z); u indexes W, v indexes H
        const float u = (p == 0) ? cx : (p == 1) ? cy : cx;
        const float v = (p == 0) ? cy : cz;

        const float fx = (u + 1.0f) * 0.5f * (RES - 1);
        const float fy = (v + 1.0f) * 0.5f * (RES - 1);
        const float x0f = floorf(fx), y0f = floorf(fy);
        const float wx = fx - x0f,  wy = fy - y0f;
        const int x0 = (int)x0f, y0 = (int)y0f;       // fx,fy in [0,255] -> x0,y0 in [0,255]
        const bool vx1 = (x0 + 1) < RES;
        const bool vy1 = (y0 + 1) < RES;
        const int x1 = vx1 ? x0 + 1 : RES - 1;
        const int y1 = vy1 ? y0 + 1 : RES - 1;

        float w00 = (1.0f - wx) * (1.0f - wy);
        float w01 = wx * (1.0f - wy);
        float w10 = (1.0f - wx) * wy;
        float w11 = wx * wy;
        if (!vx1) { w01 = 0.0f; w11 = 0.0f; }
        if (!vy1) { w10 = 0.0f; w11 = 0.0f; }

        const size_t bp = (size_t)(b * 3 + p);

        if (TRANSPOSED) {
            const size_t planeOff = bp * (RES * RES) * NCH;
            const float4* r00 = (const float4*)(planes + planeOff + ((size_t)y0 * RES + x0) * NCH);
            const float4* r01 = (const float4*)(planes + planeOff + ((size_t)y0 * RES + x1) * NCH);
            const float4* r10 = (const float4*)(planes + planeOff + ((size_t)y1 * RES + x0) * NCH);
            const float4* r11 = (const float4*)(planes + planeOff + ((size_t)y1 * RES + x1) * NCH);
            #pragma unroll
            for (int q = 0; q < NCH / 4; ++q) {
                const float4 a00 = r00[q];
                const float4 a01 = r01[q];
                const float4 a10 = r10[q];
                const float4 a11 = r11[q];
                float s0 = a00.x * w00; s0 = fmaf(a01.x, w01, s0); s0 = fmaf(a10.x, w10, s0); s0 = fmaf(a11.x, w11, s0);
                float s1 = a00.y * w00; s1 = fmaf(a01.y, w01, s1); s1 = fmaf(a10.y, w10, s1); s1 = fmaf(a11.y, w11, s1);
                float s2 = a00.z * w00; s2 = fmaf(a01.z, w01, s2); s2 = fmaf(a10.z, w10, s2); s2 = fmaf(a11.z, w11, s2);
                float s3 = a00.w * w00; s3 = fmaf(a01.w, w01, s3); s3 = fmaf(a10.w, w10, s3); s3 = fmaf(a11.w, w11, s3);
                if (p == 0) {
                    feat[4 * q + 0] = s0; feat[4 * q + 1] = s1; feat[4 * q + 2] = s2; feat[4 * q + 3] = s3;
                } else {
                    feat[4 * q + 0] *= s0; feat[4 * q + 1] *= s1; feat[4 * q + 2] *= s2; feat[4 * q + 3] *= s3;
                }
            }
        } else {
            // original [c][y][x] layout: channel stride RES*RES
            const float* base = planes + bp * NCH * RES * RES;
            const float* p00 = base + (size_t)y0 * RES + x0;
            const float* p01 = base + (size_t)y0 * RES + x1;
            const float* p10 = base + (size_t)y1 * RES + x0;
            const float* p11 = base + (size_t)y1 * RES + x1;
            #pragma unroll
            for (int c = 0; c < NCH; ++c) {
                const size_t off = (size_t)c * RES * RES;
                float s = p00[off] * w00;
                s = fmaf(p01[off], w01, s);
                s = fmaf(p10[off], w10, s);
                s = fmaf(p11[off], w11, s);
                if (p == 0) feat[c] = s; else feat[c] *= s;
            }
        }
    }

    // ---- layer 0: h0 = relu(W0 @ feat + b0)   (fully unrolled -> h0 in VGPRs)
    float h0[128];
    #pragma unroll
    for (int g = 0; g < 128; ++g) {
        const float* wr = w0 + g * NCH;             // uniform -> s_load
        float aA = b0[g], aB = 0.0f;
        #pragma unroll
        for (int c = 0; c < NCH; c += 2) {
            aA = fmaf(wr[c],     feat[c],     aA);
            aB = fmaf(wr[c + 1], feat[c + 1], aB);
        }
        h0[g] = fmaxf(aA + aB, 0.0f);
    }

    // ---- layer 1 + layer 2 fused: out = b2 + sum_g w2[g]*relu(W1[g]·h0 + b1[g])
    float o = b2[0];
    for (int g = 0; g < 128; ++g) {                 // dynamic outer loop
        const float* wr = w1 + g * 128;             // uniform -> s_load
        float aA = b1[g], aB = 0.0f, aC = 0.0f, aD = 0.0f;
        #pragma unroll
        for (int h = 0; h < 128; h += 4) {
            aA = fmaf(wr[h],     h0[h],     aA);
            aB = fmaf(wr[h + 1], h0[h + 1], aB);
            aC = fmaf(wr[h + 2], h0[h + 2], aC);
            aD = fmaf(wr[h + 3], h0[h + 3], aD);
        }
        const float acc = (aA + aB) + (aC + aD);
        o = fmaf(fmaxf(acc, 0.0f), w2[g], o);
    }

    out[t] = o;
}

// ---------------------------------------------------------------------------
extern "C" void kernel_launch(void* const* d_in, const int* in_sizes, int n_in,
                              void* d_out, int out_size, void* d_ws, size_t ws_size,
                              hipStream_t stream)
{
    const float* trip   = (const float*)d_in[0];
    const float* coords = (const float*)d_in[1];
    const float* w0     = (const float*)d_in[2];
    const float* b0     = (const float*)d_in[3];
    const float* w1     = (const float*)d_in[4];
    const float* b1     = (const float*)d_in[5];
    const float* w2     = (const float*)d_in[6];
    const float* b2     = (const float*)d_in[7];
    float* out = (float*)d_out;

    const int nPoints = NB * NPT;                      // 524288
    const int nBlocks = nPoints / 256;                 // 2048

    const size_t transposedBytes = (size_t)NB * 3 * NCH * RES * RES * sizeof(float);

    if (ws_size >= transposedBytes) {
        float* tws = (float*)d_ws;
        dim3 tg(RES / 64, RES, NB * 3);                // (4, 256, 12)
        transpose_kernel<<<tg, 256, 0, stream>>>(trip, tws);
        fused_kernel<true><<<nBlocks, 256, 0, stream>>>(
            tws, coords, w0, b0, w1, b1, w2, b2, out);
    } else {
        fused_kernel<false><<<nBlocks, 256, 0, stream>>>(
            trip, coords, w0, b0, w1, b1, w2, b2, out);
    }
}

// Round 3
// 495.238 us; speedup vs baseline: 1.9446x; 1.9446x over previous
//
#include <hip/hip_runtime.h>
#include <hip/hip_bf16.h>
#include <cstddef>

#define RES 256
#define NCH 32
#define NPT 131072   // points per batch
#define NB  4

typedef _Float16 half8 __attribute__((ext_vector_type(8)));
typedef float    f32x4 __attribute__((ext_vector_type(4)));

#define FEAT_STRIDE 40    // fp16 elems per feat row (32 + pad, 80B rows, 16B-aligned)
#define H0_STRIDE   136   // fp16 elems per h0 row (128 + pad, 272B rows, 16B-aligned)

// ---------------------------------------------------------------------------
// Transpose [bp][c][y][x] -> [bp][y][x][c], coalesced both directions.
// One block per (bp, y) row: 32c x 256x = 32 KB through LDS.
// ---------------------------------------------------------------------------
__global__ __launch_bounds__(256) void transpose_kernel(
    const float* __restrict__ in, float* __restrict__ out)
{
    __shared__ float tile[NCH][RES + 1];
    const int bp = blockIdx.y;           // 0..11
    const int y  = blockIdx.x;           // 0..255
    const int t  = threadIdx.x;

    const float* src = in + (size_t)bp * NCH * RES * RES + (size_t)y * RES;
    #pragma unroll
    for (int c = 0; c < NCH; ++c)
        tile[c][t] = src[(size_t)c * RES * RES + t];   // 1KB contiguous per instr
    __syncthreads();

    float4* dst = (float4*)(out + ((size_t)bp * RES * RES + (size_t)y * RES) * NCH);
    #pragma unroll
    for (int i = 0; i < 8; ++i) {
        const int j = i * 256 + t;       // float4 index 0..2047, coalesced
        const int x = j >> 3, cq = j & 7;
        float4 v;
        v.x = tile[cq * 4 + 0][x];
        v.y = tile[cq * 4 + 1][x];
        v.z = tile[cq * 4 + 2][x];
        v.w = tile[cq * 4 + 3][x];
        dst[j] = v;
    }
}

// ---------------------------------------------------------------------------
// Convert weights to fp16 with scaling: w0h = fp16(w0*16), w1h = fp16(w1).
// (feat is scaled x256 at sampling; net h0 scale = 4096, undone via w2/4096.)
// ---------------------------------------------------------------------------
__global__ __launch_bounds__(256) void prep_weights(
    const float* __restrict__ w0, const float* __restrict__ w1,
    _Float16* __restrict__ w0h, _Float16* __restrict__ w1h)
{
    const int i = blockIdx.x * 256 + threadIdx.x;   // grid 64*256 = 16384
    if (i < 128 * NCH) w0h[i] = (_Float16)(w0[i] * 16.0f);
    if (i < 128 * 128) w1h[i] = (_Float16)w1[i];
}

// ---------------------------------------------------------------------------
// Fused sampler + MFMA MLP. Block = 128 points, 4 waves; each wave owns 32
// points end-to-end (sample -> featLDS -> L0 MFMA -> h0LDS -> L1 MFMA -> out).
// MFMA 16x16x32 f16 layouts (verified m89/m120):
//   A: lane holds A[m=lane&15][k=quad*8+j]   (8 contiguous k)
//   B: lane holds B[k=quad*8+j][n=lane&15] = W[n][k] row-major 8-contig reads
//   C/D: col n = lane&15, row m = quad*4+reg
// ---------------------------------------------------------------------------
__global__ __launch_bounds__(256) void mlp_kernel(
    const float* __restrict__ planesT,    // [12][256][256][32] f32
    const _Float16* __restrict__ w0h,     // [128][32]  (x16 scale)
    const _Float16* __restrict__ w1h,     // [128][128]
    const float* __restrict__ coords,
    const float* __restrict__ b0, const float* __restrict__ b1,
    const float* __restrict__ w2, const float* __restrict__ b2,
    float* __restrict__ out)
{
    __shared__ __align__(16) _Float16 featLDS[128 * FEAT_STRIDE];      // 10 KB
    __shared__ __align__(16) _Float16 h0LDS[4][32 * H0_STRIDE];        // 34 KB

    const int tid  = threadIdx.x;
    const int wv   = tid >> 6;
    const int lane = tid & 63;
    const int l15  = lane & 15;
    const int quad = lane >> 4;

    // ================= phase 1: bilinear sample, 2 threads/point ===========
    {
        const int p  = tid >> 1;                    // block-local point 0..127
        const int hf = tid & 1;                     // channel half (0: ch0-15, 1: ch16-31)
        const int gp = blockIdx.x * 128 + p;
        const int b  = gp >> 17;                    // NPT = 2^17
        const float cx = coords[(size_t)gp * 3 + 0];
        const float cy = coords[(size_t)gp * 3 + 1];
        const float cz = coords[(size_t)gp * 3 + 2];

        float f[16];
        #pragma unroll
        for (int pl = 0; pl < 3; ++pl) {
            const float u = (pl == 0) ? cx : (pl == 1) ? cy : cx;
            const float v = (pl == 0) ? cy : cz;

            const float fx = (u + 1.0f) * 0.5f * (RES - 1);
            const float fy = (v + 1.0f) * 0.5f * (RES - 1);
            const float x0f = floorf(fx), y0f = floorf(fy);
            const float wx = fx - x0f, wy = fy - y0f;
            const int x0 = (int)x0f, y0 = (int)y0f;
            const bool vx1 = (x0 + 1) < RES;
            const bool vy1 = (y0 + 1) < RES;
            const int x1 = vx1 ? x0 + 1 : RES - 1;
            const int y1 = vy1 ? y0 + 1 : RES - 1;

            float w00 = (1.0f - wx) * (1.0f - wy);
            float w01 = wx * (1.0f - wy);
            float w10 = (1.0f - wx) * wy;
            float w11 = wx * wy;
            if (!vx1) { w01 = 0.0f; w11 = 0.0f; }
            if (!vy1) { w10 = 0.0f; w11 = 0.0f; }

            const float* base = planesT
                + ((size_t)(b * 3 + pl) * RES * RES) * NCH + hf * 16;
            const float4* r00 = (const float4*)(base + (size_t)(y0 * RES + x0) * NCH);
            const float4* r01 = (const float4*)(base + (size_t)(y0 * RES + x1) * NCH);
            const float4* r10 = (const float4*)(base + (size_t)(y1 * RES + x0) * NCH);
            const float4* r11 = (const float4*)(base + (size_t)(y1 * RES + x1) * NCH);

            #pragma unroll
            for (int q = 0; q < 4; ++q) {
                const float4 v00 = r00[q], v01 = r01[q], v10 = r10[q], v11 = r11[q];
                float s0 = fmaf(v11.x, w11, fmaf(v10.x, w10, fmaf(v01.x, w01, v00.x * w00)));
                float s1 = fmaf(v11.y, w11, fmaf(v10.y, w10, fmaf(v01.y, w01, v00.y * w00)));
                float s2 = fmaf(v11.z, w11, fmaf(v10.z, w10, fmaf(v01.z, w01, v00.z * w00)));
                float s3 = fmaf(v11.w, w11, fmaf(v10.w, w10, fmaf(v01.w, w01, v00.w * w00)));
                if (pl == 0) {
                    f[4*q+0] = s0; f[4*q+1] = s1; f[4*q+2] = s2; f[4*q+3] = s3;
                } else {
                    f[4*q+0] *= s0; f[4*q+1] *= s1; f[4*q+2] *= s2; f[4*q+3] *= s3;
                }
            }
        }
        // scale x256 and pack to fp16, two 16B LDS stores  (note the hf*16!)
        half8 hv0, hv1;
        #pragma unroll
        for (int j = 0; j < 8; ++j) {
            hv0[j] = (_Float16)(f[j] * 256.0f);
            hv1[j] = (_Float16)(f[8 + j] * 256.0f);
        }
        *(half8*)&featLDS[p * FEAT_STRIDE + hf * 16 + 0] = hv0;
        *(half8*)&featLDS[p * FEAT_STRIDE + hf * 16 + 8] = hv1;
    }
    __syncthreads();

    const int m0 = wv * 32;   // wave's first block-local point

    // ================= layer 0: [32pts x 32ch] @ W0^T -> h0 [32 x 128] ======
    half8 a0[2];
    #pragma unroll
    for (int mt = 0; mt < 2; ++mt)
        a0[mt] = *(const half8*)&featLDS[(m0 + mt * 16 + l15) * FEAT_STRIDE + quad * 8];

    f32x4 acc0[2][8];
    #pragma unroll
    for (int mt = 0; mt < 2; ++mt)
        #pragma unroll
        for (int nt = 0; nt < 8; ++nt)
            acc0[mt][nt] = (f32x4){0.f, 0.f, 0.f, 0.f};

    #pragma unroll
    for (int nt = 0; nt < 8; ++nt) {
        const half8 bfr = *(const half8*)&w0h[(nt * 16 + l15) * NCH + quad * 8];
        #pragma unroll
        for (int mt = 0; mt < 2; ++mt)
            acc0[mt][nt] = __builtin_amdgcn_mfma_f32_16x16x32_f16(
                a0[mt], bfr, acc0[mt][nt], 0, 0, 0);
    }

    // bias + relu -> fp16 -> h0LDS (C-layout scatter writes; A-layout reads)
    float b0v[8];
    #pragma unroll
    for (int nt = 0; nt < 8; ++nt) b0v[nt] = b0[nt * 16 + l15] * 4096.0f;

    #pragma unroll
    for (int mt = 0; mt < 2; ++mt)
        #pragma unroll
        for (int nt = 0; nt < 8; ++nt)
            #pragma unroll
            for (int r = 0; r < 4; ++r) {
                const float hval = fmaxf(acc0[mt][nt][r] + b0v[nt], 0.0f);
                h0LDS[wv][(mt * 16 + quad * 4 + r) * H0_STRIDE + nt * 16 + l15]
                    = (_Float16)hval;
            }

    // ================= layer 1: [32 x 128] @ W1^T -> h1 [32 x 128] ==========
    half8 a1[2][4];
    #pragma unroll
    for (int mt = 0; mt < 2; ++mt)
        #pragma unroll
        for (int ks = 0; ks < 4; ++ks)
            a1[mt][ks] = *(const half8*)
                &h0LDS[wv][(mt * 16 + l15) * H0_STRIDE + ks * 32 + quad * 8];

    f32x4 acc1[2][8];
    #pragma unroll
    for (int mt = 0; mt < 2; ++mt)
        #pragma unroll
        for (int nt = 0; nt < 8; ++nt)
            acc1[mt][nt] = (f32x4){0.f, 0.f, 0.f, 0.f};

    #pragma unroll
    for (int nt = 0; nt < 8; ++nt) {
        #pragma unroll
        for (int ks = 0; ks < 4; ++ks) {
            const half8 bfr = *(const half8*)
                &w1h[(nt * 16 + l15) * 128 + ks * 32 + quad * 8];
            #pragma unroll
            for (int mt = 0; mt < 2; ++mt)
                acc1[mt][nt] = __builtin_amdgcn_mfma_f32_16x16x32_f16(
                    a1[mt][ks], bfr, acc1[mt][nt], 0, 0, 0);
        }
    }

    // ================= layer 2 epilogue: out = sum_g w2[g]*relu(h1+b1) + b2 =
    float b1v[8], w2s[8];
    #pragma unroll
    for (int nt = 0; nt < 8; ++nt) {
        b1v[nt] = b1[nt * 16 + l15] * 4096.0f;
        w2s[nt] = w2[nt * 16 + l15] * (1.0f / 4096.0f);
    }

    float part[2][4];
    #pragma unroll
    for (int mt = 0; mt < 2; ++mt)
        #pragma unroll
        for (int r = 0; r < 4; ++r) part[mt][r] = 0.0f;

    #pragma unroll
    for (int mt = 0; mt < 2; ++mt)
        #pragma unroll
        for (int nt = 0; nt < 8; ++nt) {
            const f32x4 A = acc1[mt][nt];
            #pragma unroll
            for (int r = 0; r < 4; ++r)
                part[mt][r] = fmaf(w2s[nt], fmaxf(A[r] + b1v[nt], 0.0f), part[mt][r]);
        }

    // reduce across the 16 lanes (l15) of each quad-group
    #pragma unroll
    for (int mt = 0; mt < 2; ++mt)
        #pragma unroll
        for (int r = 0; r < 4; ++r) {
            float s = part[mt][r];
            s += __shfl_xor(s, 1);
            s += __shfl_xor(s, 2);
            s += __shfl_xor(s, 4);
            s += __shfl_xor(s, 8);
            part[mt][r] = s;
        }

    if (l15 == 0) {
        const float bias2 = b2[0];
        const int base = blockIdx.x * 128 + m0;
        #pragma unroll
        for (int mt = 0; mt < 2; ++mt)
            #pragma unroll
            for (int r = 0; r < 4; ++r)
                out[base + mt * 16 + quad * 4 + r] = part[mt][r] + bias2;
    }
}

// ---------------------------------------------------------------------------
// Fallback (ws too small): round-1 fused fp32 kernel on original layout.
// ---------------------------------------------------------------------------
__global__ __launch_bounds__(256) void fused_fallback(
    const float* __restrict__ planes, const float* __restrict__ coords,
    const float* __restrict__ w0, const float* __restrict__ b0,
    const float* __restrict__ w1, const float* __restrict__ b1,
    const float* __restrict__ w2, const float* __restrict__ b2,
    float* __restrict__ out)
{
    const int t = blockIdx.x * 256 + threadIdx.x;
    const int b = t >> 17;
    const float cx = coords[(size_t)t * 3 + 0];
    const float cy = coords[(size_t)t * 3 + 1];
    const float cz = coords[(size_t)t * 3 + 2];
    float feat[NCH];
    #pragma unroll
    for (int p = 0; p < 3; ++p) {
        const float u = (p == 0) ? cx : (p == 1) ? cy : cx;
        const float v = (p == 0) ? cy : cz;
        const float fx = (u + 1.0f) * 0.5f * (RES - 1);
        const float fy = (v + 1.0f) * 0.5f * (RES - 1);
        const float x0f = floorf(fx), y0f = floorf(fy);
        const float wx = fx - x0f, wy = fy - y0f;
        const int x0 = (int)x0f, y0 = (int)y0f;
        const bool vx1 = (x0 + 1) < RES, vy1 = (y0 + 1) < RES;
        const int x1 = vx1 ? x0 + 1 : RES - 1;
        const int y1 = vy1 ? y0 + 1 : RES - 1;
        float w00 = (1.0f - wx) * (1.0f - wy), w01 = wx * (1.0f - wy);
        float w10 = (1.0f - wx) * wy, w11 = wx * wy;
        if (!vx1) { w01 = 0.0f; w11 = 0.0f; }
        if (!vy1) { w10 = 0.0f; w11 = 0.0f; }
        const float* base = planes + (size_t)(b * 3 + p) * NCH * RES * RES;
        const float* p00 = base + (size_t)y0 * RES + x0;
        const float* p01 = base + (size_t)y0 * RES + x1;
        const float* p10 = base + (size_t)y1 * RES + x0;
        const float* p11 = base + (size_t)y1 * RES + x1;
        #pragma unroll
        for (int c = 0; c < NCH; ++c) {
            const size_t off = (size_t)c * RES * RES;
            float s = p00[off] * w00;
            s = fmaf(p01[off], w01, s);
            s = fmaf(p10[off], w10, s);
            s = fmaf(p11[off], w11, s);
            if (p == 0) feat[c] = s; else feat[c] *= s;
        }
    }
    float h0[128];
    #pragma unroll
    for (int g = 0; g < 128; ++g) {
        const float* wr = w0 + g * NCH;
        float aA = b0[g], aB = 0.0f;
        #pragma unroll
        for (int c = 0; c < NCH; c += 2) {
            aA = fmaf(wr[c], feat[c], aA);
            aB = fmaf(wr[c + 1], feat[c + 1], aB);
        }
        h0[g] = fmaxf(aA + aB, 0.0f);
    }
    float o = b2[0];
    for (int g = 0; g < 128; ++g) {
        const float* wr = w1 + g * 128;
        float aA = b1[g], aB = 0.0f, aC = 0.0f, aD = 0.0f;
        #pragma unroll
        for (int h = 0; h < 128; h += 4) {
            aA = fmaf(wr[h], h0[h], aA);
            aB = fmaf(wr[h + 1], h0[h + 1], aB);
            aC = fmaf(wr[h + 2], h0[h + 2], aC);
            aD = fmaf(wr[h + 3], h0[h + 3], aD);
        }
        o = fmaf(fmaxf((aA + aB) + (aC + aD), 0.0f), w2[g], o);
    }
    out[t] = o;
}

// ---------------------------------------------------------------------------
extern "C" void kernel_launch(void* const* d_in, const int* in_sizes, int n_in,
                              void* d_out, int out_size, void* d_ws, size_t ws_size,
                              hipStream_t stream)
{
    const float* trip   = (const float*)d_in[0];
    const float* coords = (const float*)d_in[1];
    const float* w0     = (const float*)d_in[2];
    const float* b0     = (const float*)d_in[3];
    const float* w1     = (const float*)d_in[4];
    const float* b1     = (const float*)d_in[5];
    const float* w2     = (const float*)d_in[6];
    const float* b2     = (const float*)d_in[7];
    float* out = (float*)d_out;

    const size_t planesTBytes = (size_t)NB * 3 * NCH * RES * RES * sizeof(float); // 100663296
    const size_t w0hBytes = 128 * NCH * sizeof(_Float16);                          // 8192
    const size_t w1hBytes = 128 * 128 * sizeof(_Float16);                          // 32768
    const size_t needed = planesTBytes + w0hBytes + w1hBytes;

    if (ws_size >= needed) {
        float* planesT   = (float*)d_ws;
        _Float16* w0h    = (_Float16*)((char*)d_ws + planesTBytes);
        _Float16* w1h    = (_Float16*)((char*)d_ws + planesTBytes + w0hBytes);

        transpose_kernel<<<dim3(RES, NB * 3), 256, 0, stream>>>(trip, planesT);
        prep_weights<<<64, 256, 0, stream>>>(w0, w1, w0h, w1h);
        mlp_kernel<<<(NB * NPT) / 128, 256, 0, stream>>>(
            planesT, w0h, w1h, coords, b0, b1, w2, b2, out);
    } else {
        fused_fallback<<<(NB * NPT) / 256, 256, 0, stream>>>(
            trip, coords, w0, b0, w1, b1, w2, b2, out);
    }
}

// Round 4
// 329.761 us; speedup vs baseline: 2.9204x; 1.5018x over previous
//
#include <hip/hip_runtime.h>
#include <hip/hip_bf16.h>
#include <cstddef>

#define RES 256
#define NCH 32
#define NPT 131072   // points per batch
#define NB  4

typedef _Float16 half8 __attribute__((ext_vector_type(8)));
typedef float    f32x4 __attribute__((ext_vector_type(4)));

#define H0_STRIDE 136   // fp16 elems per h0 row (128 + 8 pad, 16B-aligned rows)

// ---------------------------------------------------------------------------
// Transpose + fp16 convert: [bp][c][y][x] f32 -> [bp][y][x][c] f16.
// One block per (bp,y) row. float4 global loads, b128 LDS writes,
// broadcast LDS reads (bank = (4k+x')%32, 4-lane same-address broadcast).
// ---------------------------------------------------------------------------
__global__ __launch_bounds__(256) void transpose_fp16_kernel(
    const float* __restrict__ in, _Float16* __restrict__ out)
{
    __shared__ float tile[NCH][260];      // 260: multiple of 4 -> 16B-aligned rows
    const int bp = blockIdx.y;            // 0..11
    const int y  = blockIdx.x;            // 0..255
    const int t  = threadIdx.x;

    const float4* src4 = (const float4*)(in + (size_t)bp * NCH * RES * RES
                                            + (size_t)y * RES);
    const int lane4 = t & 63;             // float4 column 0..63
    const int cw    = t >> 6;             // 0..3
    #pragma unroll
    for (int i = 0; i < 8; ++i) {
        const int c = i * 4 + cw;
        const float4 v = src4[(size_t)c * (RES * RES / 4) + lane4];
        *(float4*)&tile[c][lane4 * 4] = v;
    }
    __syncthreads();

    _Float16* dst = out + ((size_t)bp * RES * RES + (size_t)y * RES) * NCH;
    #pragma unroll
    for (int i = 0; i < 4; ++i) {
        const int j  = i * 256 + t;       // 0..1023 half8-chunks
        const int x  = j >> 2;            // texel 0..255
        const int cg = j & 3;             // channel-group of 8
        half8 h;
        #pragma unroll
        for (int k = 0; k < 8; ++k)
            h[k] = (_Float16)tile[cg * 8 + k][x];
        *(half8*)&dst[(size_t)x * NCH + cg * 8] = h;   // 16B, coalesced 1KB/wave
    }
}

// ---------------------------------------------------------------------------
// Convert weights to fp16 with scaling: w0h = fp16(w0*16), w1h = fp16(w1).
// (feat scaled x256 at sampling; net h0 scale 4096, undone via w2/4096.)
// ---------------------------------------------------------------------------
__global__ __launch_bounds__(256) void prep_weights(
    const float* __restrict__ w0, const float* __restrict__ w1,
    _Float16* __restrict__ w0h, _Float16* __restrict__ w1h)
{
    const int i = blockIdx.x * 256 + threadIdx.x;   // grid 64*256 = 16384
    if (i < 128 * NCH) w0h[i] = (_Float16)(w0[i] * 16.0f);
    if (i < 128 * 128) w1h[i] = (_Float16)w1[i];
}

// ---------------------------------------------------------------------------
// Sampler: 2 threads per point (hf = channel half). No LDS, high occupancy,
// all 12 corner loads independent -> deep memory-level parallelism.
// Writes feat fp16 (x256 scale) [point][32].
// ---------------------------------------------------------------------------
__global__ __launch_bounds__(256, 4) void sample_kernel(
    const _Float16* __restrict__ planesT,   // [12][256][256][32] f16
    const float* __restrict__ coords,
    _Float16* __restrict__ featOut)         // [NB*NPT][32] f16
{
    const int gid = blockIdx.x * 256 + threadIdx.x;   // 0..2^20-1
    const int pt  = gid >> 1;
    const int hf  = gid & 1;
    const int b   = pt >> 17;                         // NPT = 2^17

    const float cx = coords[(size_t)pt * 3 + 0];
    const float cy = coords[(size_t)pt * 3 + 1];
    const float cz = coords[(size_t)pt * 3 + 2];

    float f[3][16];
    #pragma unroll
    for (int pl = 0; pl < 3; ++pl) {
        const float u = (pl == 0) ? cx : (pl == 1) ? cy : cx;
        const float v = (pl == 0) ? cy : cz;

        const float fx = (u + 1.0f) * 0.5f * (RES - 1);
        const float fy = (v + 1.0f) * 0.5f * (RES - 1);
        const float x0f = floorf(fx), y0f = floorf(fy);
        const float wx = fx - x0f, wy = fy - y0f;
        const int x0 = (int)x0f, y0 = (int)y0f;
        const bool vx1 = (x0 + 1) < RES;
        const bool vy1 = (y0 + 1) < RES;
        const int x1 = vx1 ? x0 + 1 : RES - 1;
        const int y1 = vy1 ? y0 + 1 : RES - 1;

        float w00 = (1.0f - wx) * (1.0f - wy);
        float w01 = wx * (1.0f - wy);
        float w10 = (1.0f - wx) * wy;
        float w11 = wx * wy;
        if (!vx1) { w01 = 0.0f; w11 = 0.0f; }
        if (!vy1) { w10 = 0.0f; w11 = 0.0f; }

        const _Float16* base = planesT
            + ((size_t)(b * 3 + pl) * RES * RES) * NCH + hf * 16;

        const half8* p00 = (const half8*)(base + (size_t)(y0 * RES + x0) * NCH);
        const half8* p01 = (const half8*)(base + (size_t)(y0 * RES + x1) * NCH);
        const half8* p10 = (const half8*)(base + (size_t)(y1 * RES + x0) * NCH);
        const half8* p11 = (const half8*)(base + (size_t)(y1 * RES + x1) * NCH);

        const half8 a00 = p00[0], b00 = p00[1];
        const half8 a01 = p01[0], b01 = p01[1];
        const half8 a10 = p10[0], b10 = p10[1];
        const half8 a11 = p11[0], b11 = p11[1];

        #pragma unroll
        for (int k = 0; k < 8; ++k) {
            f[pl][k] = fmaf((float)a11[k], w11, fmaf((float)a10[k], w10,
                       fmaf((float)a01[k], w01, (float)a00[k] * w00)));
            f[pl][8 + k] = fmaf((float)b11[k], w11, fmaf((float)b10[k], w10,
                           fmaf((float)b01[k], w01, (float)b00[k] * w00)));
        }
    }

    half8 o0, o1;
    #pragma unroll
    for (int k = 0; k < 8; ++k) {
        o0[k] = (_Float16)(f[0][k]     * f[1][k]     * f[2][k]     * 256.0f);
        o1[k] = (_Float16)(f[0][8 + k] * f[1][8 + k] * f[2][8 + k] * 256.0f);
    }
    _Float16* dst = featOut + (size_t)pt * NCH + hf * 16;
    *(half8*)&dst[0] = o0;
    *(half8*)&dst[8] = o1;
}

// ---------------------------------------------------------------------------
// GEMM: feat [Npts][32] f16 -> MLP 32->128->128->1 via MFMA 16x16x32 f16.
// Block = 128 points, 4 waves; each wave owns 32 points. LDS = h0LDS only.
// Layouts (verified m89/m120 + round 3):
//   A: lane holds A[m=lane&15][k=quad*8+j]
//   B: lane holds B[k=quad*8+j][n=lane&15] = W[n][k] row-major 8-contig
//   C/D: col n = lane&15, row m = quad*4+reg
// ---------------------------------------------------------------------------
__global__ __launch_bounds__(256, 4) void gemm_kernel(
    const _Float16* __restrict__ feat,    // [NB*NPT][32] f16 (x256)
    const _Float16* __restrict__ w0h,     // [128][32]  (x16)
    const _Float16* __restrict__ w1h,     // [128][128]
    const float* __restrict__ b0, const float* __restrict__ b1,
    const float* __restrict__ w2, const float* __restrict__ b2,
    float* __restrict__ out)
{
    __shared__ __align__(16) _Float16 h0LDS[4][32 * H0_STRIDE];   // 34.8 KB

    const int tid  = threadIdx.x;
    const int wv   = tid >> 6;
    const int lane = tid & 63;
    const int l15  = lane & 15;
    const int quad = lane >> 4;

    const int m0 = blockIdx.x * 128 + wv * 32;   // wave's first global point

    // ---- layer 0: A-frags straight from global feat
    half8 a0[2];
    #pragma unroll
    for (int mt = 0; mt < 2; ++mt)
        a0[mt] = *(const half8*)&feat[(size_t)(m0 + mt * 16 + l15) * NCH + quad * 8];

    f32x4 acc0[2][8];
    #pragma unroll
    for (int mt = 0; mt < 2; ++mt)
        #pragma unroll
        for (int nt = 0; nt < 8; ++nt)
            acc0[mt][nt] = (f32x4){0.f, 0.f, 0.f, 0.f};

    #pragma unroll
    for (int nt = 0; nt < 8; ++nt) {
        const half8 bfr = *(const half8*)&w0h[(nt * 16 + l15) * NCH + quad * 8];
        #pragma unroll
        for (int mt = 0; mt < 2; ++mt)
            acc0[mt][nt] = __builtin_amdgcn_mfma_f32_16x16x32_f16(
                a0[mt], bfr, acc0[mt][nt], 0, 0, 0);
    }

    // bias + relu -> fp16 -> h0LDS (C-layout writes; A-layout reads)
    float b0v[8];
    #pragma unroll
    for (int nt = 0; nt < 8; ++nt) b0v[nt] = b0[nt * 16 + l15] * 4096.0f;

    #pragma unroll
    for (int mt = 0; mt < 2; ++mt)
        #pragma unroll
        for (int nt = 0; nt < 8; ++nt)
            #pragma unroll
            for (int r = 0; r < 4; ++r) {
                const float hval = fmaxf(acc0[mt][nt][r] + b0v[nt], 0.0f);
                h0LDS[wv][(mt * 16 + quad * 4 + r) * H0_STRIDE + nt * 16 + l15]
                    = (_Float16)hval;
            }

    // ---- layer 1
    half8 a1[2][4];
    #pragma unroll
    for (int mt = 0; mt < 2; ++mt)
        #pragma unroll
        for (int ks = 0; ks < 4; ++ks)
            a1[mt][ks] = *(const half8*)
                &h0LDS[wv][(mt * 16 + l15) * H0_STRIDE + ks * 32 + quad * 8];

    f32x4 acc1[2][8];
    #pragma unroll
    for (int mt = 0; mt < 2; ++mt)
        #pragma unroll
        for (int nt = 0; nt < 8; ++nt)
            acc1[mt][nt] = (f32x4){0.f, 0.f, 0.f, 0.f};

    #pragma unroll
    for (int nt = 0; nt < 8; ++nt) {
        #pragma unroll
        for (int ks = 0; ks < 4; ++ks) {
            const half8 bfr = *(const half8*)
                &w1h[(nt * 16 + l15) * 128 + ks * 32 + quad * 8];
            #pragma unroll
            for (int mt = 0; mt < 2; ++mt)
                acc1[mt][nt] = __builtin_amdgcn_mfma_f32_16x16x32_f16(
                    a1[mt][ks], bfr, acc1[mt][nt], 0, 0, 0);
        }
    }

    // ---- layer 2 epilogue
    float b1v[8], w2s[8];
    #pragma unroll
    for (int nt = 0; nt < 8; ++nt) {
        b1v[nt] = b1[nt * 16 + l15] * 4096.0f;
        w2s[nt] = w2[nt * 16 + l15] * (1.0f / 4096.0f);
    }

    float part[2][4];
    #pragma unroll
    for (int mt = 0; mt < 2; ++mt)
        #pragma unroll
        for (int r = 0; r < 4; ++r) part[mt][r] = 0.0f;

    #pragma unroll
    for (int mt = 0; mt < 2; ++mt)
        #pragma unroll
        for (int nt = 0; nt < 8; ++nt) {
            const f32x4 A = acc1[mt][nt];
            #pragma unroll
            for (int r = 0; r < 4; ++r)
                part[mt][r] = fmaf(w2s[nt], fmaxf(A[r] + b1v[nt], 0.0f), part[mt][r]);
        }

    #pragma unroll
    for (int mt = 0; mt < 2; ++mt)
        #pragma unroll
        for (int r = 0; r < 4; ++r) {
            float s = part[mt][r];
            s += __shfl_xor(s, 1);
            s += __shfl_xor(s, 2);
            s += __shfl_xor(s, 4);
            s += __shfl_xor(s, 8);
            part[mt][r] = s;
        }

    if (l15 == 0) {
        const float bias2 = b2[0];
        #pragma unroll
        for (int mt = 0; mt < 2; ++mt)
            #pragma unroll
            for (int r = 0; r < 4; ++r)
                out[m0 + mt * 16 + quad * 4 + r] = part[mt][r] + bias2;
    }
}

// ---------------------------------------------------------------------------
// Fallback (ws too small): round-1 fused fp32 kernel on original layout.
// ---------------------------------------------------------------------------
__global__ __launch_bounds__(256) void fused_fallback(
    const float* __restrict__ planes, const float* __restrict__ coords,
    const float* __restrict__ w0, const float* __restrict__ b0,
    const float* __restrict__ w1, const float* __restrict__ b1,
    const float* __restrict__ w2, const float* __restrict__ b2,
    float* __restrict__ out)
{
    const int t = blockIdx.x * 256 + threadIdx.x;
    const int b = t >> 17;
    const float cx = coords[(size_t)t * 3 + 0];
    const float cy = coords[(size_t)t * 3 + 1];
    const float cz = coords[(size_t)t * 3 + 2];
    float feat[NCH];
    #pragma unroll
    for (int p = 0; p < 3; ++p) {
        const float u = (p == 0) ? cx : (p == 1) ? cy : cx;
        const float v = (p == 0) ? cy : cz;
        const float fx = (u + 1.0f) * 0.5f * (RES - 1);
        const float fy = (v + 1.0f) * 0.5f * (RES - 1);
        const float x0f = floorf(fx), y0f = floorf(fy);
        const float wx = fx - x0f, wy = fy - y0f;
        const int x0 = (int)x0f, y0 = (int)y0f;
        const bool vx1 = (x0 + 1) < RES, vy1 = (y0 + 1) < RES;
        const int x1 = vx1 ? x0 + 1 : RES - 1;
        const int y1 = vy1 ? y0 + 1 : RES - 1;
        float w00 = (1.0f - wx) * (1.0f - wy), w01 = wx * (1.0f - wy);
        float w10 = (1.0f - wx) * wy, w11 = wx * wy;
        if (!vx1) { w01 = 0.0f; w11 = 0.0f; }
        if (!vy1) { w10 = 0.0f; w11 = 0.0f; }
        const float* base = planes + (size_t)(b * 3 + p) * NCH * RES * RES;
        const float* p00 = base + (size_t)y0 * RES + x0;
        const float* p01 = base + (size_t)y0 * RES + x1;
        const float* p10 = base + (size_t)y1 * RES + x0;
        const float* p11 = base + (size_t)y1 * RES + x1;
        #pragma unroll
        for (int c = 0; c < NCH; ++c) {
            const size_t off = (size_t)c * RES * RES;
            float s = p00[off] * w00;
            s = fmaf(p01[off], w01, s);
            s = fmaf(p10[off], w10, s);
            s = fmaf(p11[off], w11, s);
            if (p == 0) feat[c] = s; else feat[c] *= s;
        }
    }
    float h0[128];
    #pragma unroll
    for (int g = 0; g < 128; ++g) {
        const float* wr = w0 + g * NCH;
        float aA = b0[g], aB = 0.0f;
        #pragma unroll
        for (int c = 0; c < NCH; c += 2) {
            aA = fmaf(wr[c], feat[c], aA);
            aB = fmaf(wr[c + 1], feat[c + 1], aB);
        }
        h0[g] = fmaxf(aA + aB, 0.0f);
    }
    float o = b2[0];
    for (int g = 0; g < 128; ++g) {
        const float* wr = w1 + g * 128;
        float aA = b1[g], aB = 0.0f, aC = 0.0f, aD = 0.0f;
        #pragma unroll
        for (int h = 0; h < 128; h += 4) {
            aA = fmaf(wr[h], h0[h], aA);
            aB = fmaf(wr[h + 1], h0[h + 1], aB);
            aC = fmaf(wr[h + 2], h0[h + 2], aC);
            aD = fmaf(wr[h + 3], h0[h + 3], aD);
        }
        o = fmaf(fmaxf((aA + aB) + (aC + aD), 0.0f), w2[g], o);
    }
    out[t] = o;
}

// ---------------------------------------------------------------------------
extern "C" void kernel_launch(void* const* d_in, const int* in_sizes, int n_in,
                              void* d_out, int out_size, void* d_ws, size_t ws_size,
                              hipStream_t stream)
{
    const float* trip   = (const float*)d_in[0];
    const float* coords = (const float*)d_in[1];
    const float* w0     = (const float*)d_in[2];
    const float* b0     = (const float*)d_in[3];
    const float* w1     = (const float*)d_in[4];
    const float* b1     = (const float*)d_in[5];
    const float* w2     = (const float*)d_in[6];
    const float* b2     = (const float*)d_in[7];
    float* out = (float*)d_out;

    const size_t planesTBytes = (size_t)NB * 3 * RES * RES * NCH * 2;   // 50331648
    const size_t w0hBytes  = 128 * NCH * 2;                             // 8192
    const size_t w1hBytes  = 128 * 128 * 2;                             // 32768
    const size_t featBytes = (size_t)NB * NPT * NCH * 2;                // 33554432
    const size_t needed = planesTBytes + w0hBytes + w1hBytes + featBytes;

    if (ws_size >= needed) {
        _Float16* planesT = (_Float16*)d_ws;
        _Float16* w0h     = (_Float16*)((char*)d_ws + planesTBytes);
        _Float16* w1h     = (_Float16*)((char*)d_ws + planesTBytes + w0hBytes);
        _Float16* featWS  = (_Float16*)((char*)d_ws + planesTBytes + w0hBytes + w1hBytes);

        transpose_fp16_kernel<<<dim3(RES, NB * 3), 256, 0, stream>>>(trip, planesT);
        prep_weights<<<64, 256, 0, stream>>>(w0, w1, w0h, w1h);
        sample_kernel<<<(NB * NPT * 2) / 256, 256, 0, stream>>>(planesT, coords, featWS);
        gemm_kernel<<<(NB * NPT) / 128, 256, 0, stream>>>(
            featWS, w0h, w1h, b0, b1, w2, b2, out);
    } else {
        fused_fallback<<<(NB * NPT) / 256, 256, 0, stream>>>(
            trip, coords, w0, b0, w1, b1, w2, b2, out);
    }
}